// Round 7
// baseline (306.805 us; speedup 1.0000x reference)
//
#include <hip/hip_runtime.h>

// Problem constants
#define B_ 8
#define C_ 64
#define H_ 240
#define W_ 320
#define HW_ (H_ * W_)      // 76800
#define HW4_ (HW_ / 4)     // 19200
#define K_ 10
#define ALPHA_ 0.02f
#define DELTA_ 0.5f
#define MIN_WEIGHT_ 50.0f

#define NCH 8              // channels per k1 block (one-hot amortized over 8)
#define CB_ (C_ / NCH)     // 8 channel-blocks
#define Z1 16              // pixel splits -> 8*8*16 = 1024 blocks (4/CU exact)
#define CHUNK1 (HW4_ / Z1) // 1200 float4 per slab

// Workspace float offsets (NO memset anywhere — every word is pure-stored
// before it is read, every accumulator is zeroed by a prior kernel):
//   SL_SUMS [Z1][B*C*K]  per-z partial sums   (pure stores in k1)
//   SL_CNT  [Z1][B*K]    per-z partial counts (pure stores in k1, cb==0)
//   OFF_S2  [B*K]        zeroed by k2, atomics in k3
//   OFF_NK  [B*K]        zeroed by k2, atomics in k3
//   OFF_HP  [B]          per-batch hinge partial (pure store in k2)
//   OFF_MEANS [B*C*K]    normalized means (pure store in k2)
#define SL_SUMS 0
#define SL_CNT  (Z1 * B_ * C_ * K_)          // 81920
#define OFF_S2  (SL_CNT + Z1 * B_ * K_)      // 83200
#define OFF_NK  (OFF_S2 + B_ * K_)           // 83280
#define OFF_HP  (OFF_NK + B_ * K_)           // 83360
#define OFF_MEANS 83392

// ---------------------------------------------------------------------------
// Kernel 1: masked channel sums + cluster counts -> private z-slices.
// One-hot built once per pixel, amortized over NCH=8 channels; store-only
// epilogue (no atomics, no pre-zeroing). grid (CB_, B_, Z1), block 256.
// ---------------------------------------------------------------------------
__global__ __launch_bounds__(256) void k1_sums(
    const float* __restrict__ x, const int* __restrict__ cm,
    float* __restrict__ ws) {
  const int cb = blockIdx.x;       // channel block 0..7
  const int b = blockIdx.y;
  const int z = blockIdx.z;
  const int tid = threadIdx.x;
  const int c0 = cb * NCH;

  const int lo = z * CHUNK1;
  const int hi = lo + CHUNK1;

  const float4* __restrict__ xp =
      (const float4*)(x + (size_t)(b * C_ + c0) * HW_);
  const int4* __restrict__ cp = (const int4*)(cm + (size_t)b * HW_);

  float acc[NCH][K_];
#pragma unroll
  for (int c = 0; c < NCH; ++c)
#pragma unroll
    for (int j = 0; j < K_; ++j) acc[c][j] = 0.f;
  float cnt[K_];
#pragma unroll
  for (int j = 0; j < K_; ++j) cnt[j] = 0.f;
  const bool do_cnt = (cb == 0);

  for (int i = lo + tid; i < hi; i += 256) {
    const int4 k4 = cp[i];
    float oh0[K_], oh1[K_], oh2[K_], oh3[K_];
#pragma unroll
    for (int j = 0; j < K_; ++j) {
      oh0[j] = (k4.x == j) ? 1.f : 0.f;
      oh1[j] = (k4.y == j) ? 1.f : 0.f;
      oh2[j] = (k4.z == j) ? 1.f : 0.f;
      oh3[j] = (k4.w == j) ? 1.f : 0.f;
    }
    if (do_cnt) {
#pragma unroll
      for (int j = 0; j < K_; ++j)
        cnt[j] += (oh0[j] + oh1[j]) + (oh2[j] + oh3[j]);
    }
#pragma unroll
    for (int c = 0; c < NCH; ++c) {
      const float4 v = xp[c * HW4_ + i];
#pragma unroll
      for (int j = 0; j < K_; ++j) {
        acc[c][j] += v.x * oh0[j];
        acc[c][j] += v.y * oh1[j];
        acc[c][j] += v.z * oh2[j];
        acc[c][j] += v.w * oh3[j];
      }
    }
  }

  // wave-level shfl reduce -> LDS partials -> plain stores (no atomics)
  __shared__ float partS[4][NCH * K_];
  __shared__ float partC[4][K_];
  const int w = tid >> 6;
#pragma unroll
  for (int c = 0; c < NCH; ++c) {
#pragma unroll
    for (int j = 0; j < K_; ++j) {
      float v = acc[c][j];
#pragma unroll
      for (int off = 32; off > 0; off >>= 1) v += __shfl_down(v, off, 64);
      if ((tid & 63) == 0) partS[w][c * K_ + j] = v;
    }
  }
  if (do_cnt) {
#pragma unroll
    for (int j = 0; j < K_; ++j) {
      float v = cnt[j];
#pragma unroll
      for (int off = 32; off > 0; off >>= 1) v += __shfl_down(v, off, 64);
      if ((tid & 63) == 0) partC[w][j] = v;
    }
  }
  __syncthreads();

  float* __restrict__ slice =
      ws + SL_SUMS + z * (B_ * C_ * K_) + (b * C_ + c0) * K_;
  if (tid < NCH * K_)
    slice[tid] =
        (partS[0][tid] + partS[1][tid]) + (partS[2][tid] + partS[3][tid]);
  if (do_cnt && tid < K_) {
    ws[SL_CNT + z * (B_ * K_) + b * K_ + tid] =
        (partC[0][tid] + partC[1][tid]) + (partC[2][tid] + partC[3][tid]);
  }
}

// ---------------------------------------------------------------------------
// Kernel 2: per-batch — reduce z-slices, normalize means, write means,
// compute hinge partial, zero this batch's S2/Nk bins. grid (B_), block 256.
// ---------------------------------------------------------------------------
__global__ __launch_bounds__(256) void k2_norm(float* __restrict__ ws) {
  const int b = blockIdx.x;
  const int tid = threadIdx.x;

  float* __restrict__ means = ws + OFF_MEANS + b * C_ * K_;

  __shared__ float mlds[C_ * K_];
  __shared__ float cntl[K_];
  __shared__ float nrm[K_];
  __shared__ float hr[64];

  if (tid < K_) {
    float s = 0.f;
#pragma unroll
    for (int z = 0; z < Z1; ++z) s += ws[SL_CNT + z * (B_ * K_) + b * K_ + tid];
    cntl[tid] = s;
    // zero the k3 accumulators for this batch (stream-ordered before k3)
    ws[OFF_S2 + b * K_ + tid] = 0.f;
    ws[OFF_NK + b * K_ + tid] = 0.f;
  }
  __syncthreads();
  for (int i = tid; i < C_ * K_; i += 256) {
    float s = 0.f;
#pragma unroll
    for (int z = 0; z < Z1; ++z)
      s += ws[SL_SUMS + z * (B_ * C_ * K_) + b * C_ * K_ + i];
    mlds[i] = s / (cntl[i % K_] + 1e-10f);
  }
  __syncthreads();
  if (tid < K_) {
    float n2 = 0.f;
#pragma unroll
    for (int c = 0; c < C_; ++c) {
      const float mm = mlds[c * K_ + tid];
      n2 += mm * mm;
    }
    nrm[tid] = 1.f / fmaxf(sqrtf(n2), 1e-12f);
  }
  __syncthreads();
  for (int i = tid; i < C_ * K_; i += 256) {
    const float m = mlds[i] * nrm[i % K_];
    mlds[i] = m;
    means[i] = m;
  }
  __syncthreads();

  // hinge partial: 45 pairs, dots over LDS means
  if (tid < 45) {
    int idx = tid;
    int k = 0, l = 0;
    for (k = 0; k < K_; ++k) {
      const int row = K_ - 1 - k;
      if (idx < row) { l = k + 1 + idx; break; }
      idx -= row;
    }
    float g = 0.f;
#pragma unroll
    for (int c = 0; c < C_; ++c) g += mlds[c * K_ + k] * mlds[c * K_ + l];
    const float inter_d = 0.5f * (1.f - g);
    const float h = fmaxf(DELTA_ - inter_d, 0.f);
    hr[tid] = 2.f * h * h;  // (k,l) and (l,k)
  }
  __syncthreads();
  if (tid == 0) {
    float s = 0.f;
    for (int i = 0; i < 45; ++i) s += hr[i];
    ws[OFF_HP + b] = s;
  }
}

// ---------------------------------------------------------------------------
// Kernel 3: per-pixel intra -> S2/Nk. Barrier-free main loop (round-5
// winner); now 1-wave blocks for finer CU balance + simpler epilogue.
// grid (300, 8), block 64.
// ---------------------------------------------------------------------------
__global__ __launch_bounds__(64) void k3_intra(
    const float* __restrict__ x, const int* __restrict__ cm,
    float* __restrict__ ws) {
  const int b = blockIdx.y;
  const int tid = threadIdx.x;

  float* __restrict__ S2 = ws + OFF_S2;
  float* __restrict__ Nk = ws + OFF_NK;
  const float* __restrict__ means = ws + OFF_MEANS;

  __shared__ float mlds[C_ * K_];  // 640 floats, [c*10+k]
  __shared__ float s2w[K_];
  __shared__ float nkw[K_];

  for (int i = tid; i < C_ * K_; i += 64) mlds[i] = means[b * C_ * K_ + i];
  if (tid < K_) { s2w[tid] = 0.f; nkw[tid] = 0.f; }
  __syncthreads();

  const int p4 = blockIdx.x * 64 + tid;  // 0..19199
  const int4 k4 = ((const int4*)(cm + (size_t)b * HW_))[p4];
  const float4* __restrict__ xb =
      (const float4*)(x + (size_t)b * C_ * HW_) + p4;

  // base pointers: channel index folds into ds_read immediate offsets
  const float* __restrict__ m0 = &mlds[k4.x];
  const float* __restrict__ m1 = &mlds[k4.y];
  const float* __restrict__ m2 = &mlds[k4.z];
  const float* __restrict__ m3 = &mlds[k4.w];

  float d0 = 0.f, d1 = 0.f, d2 = 0.f, d3 = 0.f;
#pragma unroll 16
  for (int c = 0; c < C_; ++c) {
    const float4 v = xb[c * HW4_];
    d0 += v.x * m0[c * K_];
    d1 += v.y * m1[c * K_];
    d2 += v.z * m2[c * K_];
    d3 += v.w * m3[c * K_];
  }

  const float i0 = 0.5f * (1.f - d0);
  const float i1 = 0.5f * (1.f - d1);
  const float i2 = 0.5f * (1.f - d2);
  const float i3 = 0.5f * (1.f - d3);

  atomicAdd(&s2w[k4.x], i0 * i0);
  atomicAdd(&s2w[k4.y], i1 * i1);
  atomicAdd(&s2w[k4.z], i2 * i2);
  atomicAdd(&s2w[k4.w], i3 * i3);
  atomicAdd(&nkw[k4.x], i0 > ALPHA_ ? 1.f : 0.f);
  atomicAdd(&nkw[k4.y], i1 > ALPHA_ ? 1.f : 0.f);
  atomicAdd(&nkw[k4.z], i2 > ALPHA_ ? 1.f : 0.f);
  atomicAdd(&nkw[k4.w], i3 > ALPHA_ ? 1.f : 0.f);
  __syncthreads();

  if (tid < K_) {
    atomicAdd(&S2[b * K_ + tid], s2w[tid]);
    atomicAdd(&Nk[b * K_ + tid], nkw[tid]);
  }
}

// ---------------------------------------------------------------------------
// Kernel 4: tiny combine — 80 S2/Nk bins + 8 hinge partials. 1 block x 128.
// ---------------------------------------------------------------------------
__global__ __launch_bounds__(128) void k4_final(
    const float* __restrict__ ws, float* __restrict__ out) {
  const int tid = threadIdx.x;
  const float* __restrict__ S2 = ws + OFF_S2;
  const float* __restrict__ Nk = ws + OFF_NK;
  const float* __restrict__ hp = ws + OFF_HP;

  float acc_i = 0.f, acc_n = 0.f, acc_h = 0.f;
  if (tid < B_ * K_) {
    const float nk = Nk[tid];
    acc_n = nk;
    const float w = fmaxf(nk, MIN_WEIGHT_) * (float)K_;
    acc_i = S2[tid] / w;
  }
  if (tid < B_) acc_h = hp[tid];

  __shared__ float rh[128], ri[128], rn[128];
  rh[tid] = acc_h;
  ri[tid] = acc_i;
  rn[tid] = acc_n;
  __syncthreads();
  for (int s = 64; s > 0; s >>= 1) {
    if (tid < s) {
      rh[tid] += rh[tid + s];
      ri[tid] += ri[tid + s];
      rn[tid] += rn[tid + s];
    }
    __syncthreads();
  }
  if (tid == 0) {
    const float inter = rh[0] / (float)((K_ * (K_ - 1) / 2) * B_);
    float intra = ri[0] / (float)B_;
    if (!(rn[0] > 0.f)) intra = 0.f;
    out[0] = intra + inter;
    out[1] = intra;
    out[2] = inter;
  }
}

extern "C" void kernel_launch(void* const* d_in, const int* in_sizes, int n_in,
                              void* d_out, int out_size, void* d_ws, size_t ws_size,
                              hipStream_t stream) {
  const float* x = (const float*)d_in[0];
  const int* cm = (const int*)d_in[1];
  float* ws = (float*)d_ws;

  // No memset: k1 pure-stores slices; k2 zeroes S2/Nk and writes means/hp.
  k1_sums<<<dim3(CB_, B_, Z1), 256, 0, stream>>>(x, cm, ws);
  k2_norm<<<B_, 256, 0, stream>>>(ws);
  k3_intra<<<dim3(HW4_ / 64, B_), 64, 0, stream>>>(x, cm, ws);
  k4_final<<<1, 128, 0, stream>>>(ws, (float*)d_out);
}

// Round 9
// 272.319 us; speedup vs baseline: 1.1266x; 1.1266x over previous
//
#include <hip/hip_runtime.h>

// Problem constants
#define B_ 8
#define C_ 64
#define H_ 240
#define W_ 320
#define HW_ (H_ * W_)      // 76800
#define HW4_ (HW_ / 4)     // 19200
#define K_ 10
#define ALPHA_ 0.02f
#define DELTA_ 0.5f
#define MIN_WEIGHT_ 50.0f

#define NCH 4              // channels per k1 block (40 acc VGPRs — no spill;
                           // NCH=8 spilled to scratch, 103 µs in round 7)
#define CB_ (C_ / NCH)     // 16 channel-blocks
#define Z1 8               // pixel splits -> 16*8*8 = 1024 blocks (4/CU exact)
#define CHUNK1 (HW4_ / Z1) // 2400 float4 per slab

// Workspace float offsets (NO memset anywhere — every word is pure-stored
// before it is read, every accumulator is zeroed by a prior kernel):
//   SL_SUMS [Z1][B*C*K]  per-z partial sums   (pure stores in k1)
//   SL_CNT  [Z1][B*K]    per-z partial counts (pure stores in k1, cb==0)
//   OFF_S2  [B*K]        zeroed by k2, atomics in k3
//   OFF_NK  [B*K]        zeroed by k2, atomics in k3
//   OFF_HP  [B]          per-batch hinge partial (pure store in k2)
//   OFF_MEANS [B*C*K]    normalized means (pure store in k2)
#define SL_SUMS 0
#define SL_CNT  (Z1 * B_ * C_ * K_)          // 40960
#define OFF_S2  (SL_CNT + Z1 * B_ * K_)      // 41600
#define OFF_NK  (OFF_S2 + B_ * K_)           // 41680
#define OFF_HP  (OFF_NK + B_ * K_)           // 41760
#define OFF_MEANS 41792

// ---------------------------------------------------------------------------
// Kernel 1: masked channel sums + cluster counts -> private z-slices.
// Proven round-6 version, byte-for-byte. grid (CB_, B_, Z1), block 256.
// ---------------------------------------------------------------------------
__global__ __launch_bounds__(256) void k1_sums(
    const float* __restrict__ x, const int* __restrict__ cm,
    float* __restrict__ ws) {
  const int cb = blockIdx.x;
  const int b = blockIdx.y;
  const int z = blockIdx.z;
  const int tid = threadIdx.x;
  const int c0 = cb * NCH;

  const int lo = z * CHUNK1;
  const int hi = lo + CHUNK1;

  const float4* __restrict__ xp =
      (const float4*)(x + (size_t)(b * C_ + c0) * HW_);
  const int4* __restrict__ cp = (const int4*)(cm + (size_t)b * HW_);

  float acc[NCH][K_];
#pragma unroll
  for (int c = 0; c < NCH; ++c)
#pragma unroll
    for (int j = 0; j < K_; ++j) acc[c][j] = 0.f;
  float cnt[K_];
#pragma unroll
  for (int j = 0; j < K_; ++j) cnt[j] = 0.f;
  const bool do_cnt = (cb == 0);

  for (int i = lo + tid; i < hi; i += 256) {
    const int4 k4 = cp[i];
    float oh0[K_], oh1[K_], oh2[K_], oh3[K_];
#pragma unroll
    for (int j = 0; j < K_; ++j) {
      oh0[j] = (k4.x == j) ? 1.f : 0.f;
      oh1[j] = (k4.y == j) ? 1.f : 0.f;
      oh2[j] = (k4.z == j) ? 1.f : 0.f;
      oh3[j] = (k4.w == j) ? 1.f : 0.f;
    }
    if (do_cnt) {
#pragma unroll
      for (int j = 0; j < K_; ++j)
        cnt[j] += (oh0[j] + oh1[j]) + (oh2[j] + oh3[j]);
    }
#pragma unroll
    for (int c = 0; c < NCH; ++c) {
      const float4 v = xp[c * HW4_ + i];
#pragma unroll
      for (int j = 0; j < K_; ++j) {
        acc[c][j] += v.x * oh0[j];
        acc[c][j] += v.y * oh1[j];
        acc[c][j] += v.z * oh2[j];
        acc[c][j] += v.w * oh3[j];
      }
    }
  }

  // wave-level shfl reduce -> LDS partials -> plain stores (no atomics)
  __shared__ float partS[4][NCH * K_];
  __shared__ float partC[4][K_];
  const int w = tid >> 6;
#pragma unroll
  for (int c = 0; c < NCH; ++c) {
#pragma unroll
    for (int j = 0; j < K_; ++j) {
      float v = acc[c][j];
#pragma unroll
      for (int off = 32; off > 0; off >>= 1) v += __shfl_down(v, off, 64);
      if ((tid & 63) == 0) partS[w][c * K_ + j] = v;
    }
  }
  if (do_cnt) {
#pragma unroll
    for (int j = 0; j < K_; ++j) {
      float v = cnt[j];
#pragma unroll
      for (int off = 32; off > 0; off >>= 1) v += __shfl_down(v, off, 64);
      if ((tid & 63) == 0) partC[w][j] = v;
    }
  }
  __syncthreads();

  float* __restrict__ slice =
      ws + SL_SUMS + z * (B_ * C_ * K_) + (b * C_ + c0) * K_;
  if (tid < NCH * K_)
    slice[tid] =
        (partS[0][tid] + partS[1][tid]) + (partS[2][tid] + partS[3][tid]);
  if (do_cnt && tid < K_) {
    ws[SL_CNT + z * (B_ * K_) + b * K_ + tid] =
        (partC[0][tid] + partC[1][tid]) + (partC[2][tid] + partC[3][tid]);
  }
}

// ---------------------------------------------------------------------------
// Kernel 2: per-batch — reduce z-slices, normalize means, write means,
// compute hinge partial, zero this batch's S2/Nk bins. grid (B_), block 256.
// ---------------------------------------------------------------------------
__global__ __launch_bounds__(256) void k2_norm(float* __restrict__ ws) {
  const int b = blockIdx.x;
  const int tid = threadIdx.x;

  float* __restrict__ means = ws + OFF_MEANS + b * C_ * K_;

  __shared__ float mlds[C_ * K_];
  __shared__ float cntl[K_];
  __shared__ float nrm[K_];
  __shared__ float hr[64];

  if (tid < K_) {
    float s = 0.f;
#pragma unroll
    for (int z = 0; z < Z1; ++z) s += ws[SL_CNT + z * (B_ * K_) + b * K_ + tid];
    cntl[tid] = s;
    // zero the k3 accumulators for this batch (stream-ordered before k3)
    ws[OFF_S2 + b * K_ + tid] = 0.f;
    ws[OFF_NK + b * K_ + tid] = 0.f;
  }
  __syncthreads();
  for (int i = tid; i < C_ * K_; i += 256) {
    float s = 0.f;
#pragma unroll
    for (int z = 0; z < Z1; ++z)
      s += ws[SL_SUMS + z * (B_ * C_ * K_) + b * C_ * K_ + i];
    mlds[i] = s / (cntl[i % K_] + 1e-10f);
  }
  __syncthreads();
  if (tid < K_) {
    float n2 = 0.f;
#pragma unroll
    for (int c = 0; c < C_; ++c) {
      const float mm = mlds[c * K_ + tid];
      n2 += mm * mm;
    }
    nrm[tid] = 1.f / fmaxf(sqrtf(n2), 1e-12f);
  }
  __syncthreads();
  for (int i = tid; i < C_ * K_; i += 256) {
    const float m = mlds[i] * nrm[i % K_];
    mlds[i] = m;
    means[i] = m;
  }
  __syncthreads();

  // hinge partial: 45 pairs, dots over LDS means
  if (tid < 45) {
    int idx = tid;
    int k = 0, l = 0;
    for (k = 0; k < K_; ++k) {
      const int row = K_ - 1 - k;
      if (idx < row) { l = k + 1 + idx; break; }
      idx -= row;
    }
    float g = 0.f;
#pragma unroll
    for (int c = 0; c < C_; ++c) g += mlds[c * K_ + k] * mlds[c * K_ + l];
    const float inter_d = 0.5f * (1.f - g);
    const float h = fmaxf(DELTA_ - inter_d, 0.f);
    hr[tid] = 2.f * h * h;  // (k,l) and (l,k)
  }
  __syncthreads();
  if (tid == 0) {
    float s = 0.f;
    for (int i = 0; i < 45; ++i) s += hr[i];
    ws[OFF_HP + b] = s;
  }
}

// ---------------------------------------------------------------------------
// Kernel 3: per-pixel intra -> S2/Nk. Round-6 winner, ONE change: block ->
// chunk mapping REVERSED so the earliest-dispatched k3 blocks read the bytes
// k1 touched last (still L3-resident) — LIFO reuse instead of FIFO thrash.
// grid (150, 8), block 128 (2 waves).
// ---------------------------------------------------------------------------
__global__ __launch_bounds__(128) void k3_intra(
    const float* __restrict__ x, const int* __restrict__ cm,
    float* __restrict__ ws) {
  const int b = blockIdx.y;
  const int tid = threadIdx.x;
  const int w = tid >> 6;          // wave 0/1

  float* __restrict__ S2 = ws + OFF_S2;
  float* __restrict__ Nk = ws + OFF_NK;
  const float* __restrict__ means = ws + OFF_MEANS;

  __shared__ float mlds[C_ * K_];  // 640 floats, [c*10+k]
  __shared__ float s2w[2 * K_];    // per-wave bins
  __shared__ float nkw[2 * K_];

  for (int i = tid; i < C_ * K_; i += 128) mlds[i] = means[b * C_ * K_ + i];
  if (tid < 2 * K_) { s2w[tid] = 0.f; nkw[tid] = 0.f; }
  __syncthreads();

  // reversed chunk order (coalescing within the block unchanged)
  const int chunk = (int)gridDim.x - 1 - (int)blockIdx.x;
  const int p4 = chunk * 128 + tid;  // 0..19199
  const int4 k4 = ((const int4*)(cm + (size_t)b * HW_))[p4];
  const float4* __restrict__ xb =
      (const float4*)(x + (size_t)b * C_ * HW_) + p4;

  const float* __restrict__ m0 = &mlds[k4.x];
  const float* __restrict__ m1 = &mlds[k4.y];
  const float* __restrict__ m2 = &mlds[k4.z];
  const float* __restrict__ m3 = &mlds[k4.w];

  float d0 = 0.f, d1 = 0.f, d2 = 0.f, d3 = 0.f;
#pragma unroll 16
  for (int c = 0; c < C_; ++c) {
    const float4 v = xb[c * HW4_];
    d0 += v.x * m0[c * K_];
    d1 += v.y * m1[c * K_];
    d2 += v.z * m2[c * K_];
    d3 += v.w * m3[c * K_];
  }

  const float i0 = 0.5f * (1.f - d0);
  const float i1 = 0.5f * (1.f - d1);
  const float i2 = 0.5f * (1.f - d2);
  const float i3 = 0.5f * (1.f - d3);

  atomicAdd(&s2w[w * K_ + k4.x], i0 * i0);
  atomicAdd(&s2w[w * K_ + k4.y], i1 * i1);
  atomicAdd(&s2w[w * K_ + k4.z], i2 * i2);
  atomicAdd(&s2w[w * K_ + k4.w], i3 * i3);
  atomicAdd(&nkw[w * K_ + k4.x], i0 > ALPHA_ ? 1.f : 0.f);
  atomicAdd(&nkw[w * K_ + k4.y], i1 > ALPHA_ ? 1.f : 0.f);
  atomicAdd(&nkw[w * K_ + k4.z], i2 > ALPHA_ ? 1.f : 0.f);
  atomicAdd(&nkw[w * K_ + k4.w], i3 > ALPHA_ ? 1.f : 0.f);
  __syncthreads();

  if (tid < K_) {
    atomicAdd(&S2[b * K_ + tid], s2w[tid] + s2w[K_ + tid]);
    atomicAdd(&Nk[b * K_ + tid], nkw[tid] + nkw[K_ + tid]);
  }
}

// ---------------------------------------------------------------------------
// Kernel 4: tiny combine — 80 S2/Nk bins + 8 hinge partials. 1 block x 128.
// ---------------------------------------------------------------------------
__global__ __launch_bounds__(128) void k4_final(
    const float* __restrict__ ws, float* __restrict__ out) {
  const int tid = threadIdx.x;
  const float* __restrict__ S2 = ws + OFF_S2;
  const float* __restrict__ Nk = ws + OFF_NK;
  const float* __restrict__ hp = ws + OFF_HP;

  float acc_i = 0.f, acc_n = 0.f, acc_h = 0.f;
  if (tid < B_ * K_) {
    const float nk = Nk[tid];
    acc_n = nk;
    const float w = fmaxf(nk, MIN_WEIGHT_) * (float)K_;
    acc_i = S2[tid] / w;
  }
  if (tid < B_) acc_h = hp[tid];

  __shared__ float rh[128], ri[128], rn[128];
  rh[tid] = acc_h;
  ri[tid] = acc_i;
  rn[tid] = acc_n;
  __syncthreads();
  for (int s = 64; s > 0; s >>= 1) {
    if (tid < s) {
      rh[tid] += rh[tid + s];
      ri[tid] += ri[tid + s];
      rn[tid] += rn[tid + s];
    }
    __syncthreads();
  }
  if (tid == 0) {
    const float inter = rh[0] / (float)((K_ * (K_ - 1) / 2) * B_);
    float intra = ri[0] / (float)B_;
    if (!(rn[0] > 0.f)) intra = 0.f;
    out[0] = intra + inter;
    out[1] = intra;
    out[2] = inter;
  }
}

extern "C" void kernel_launch(void* const* d_in, const int* in_sizes, int n_in,
                              void* d_out, int out_size, void* d_ws, size_t ws_size,
                              hipStream_t stream) {
  const float* x = (const float*)d_in[0];
  const int* cm = (const int*)d_in[1];
  float* ws = (float*)d_ws;

  // No memset: k1 pure-stores slices; k2 zeroes S2/Nk and writes means/hp.
  k1_sums<<<dim3(CB_, B_, Z1), 256, 0, stream>>>(x, cm, ws);
  k2_norm<<<B_, 256, 0, stream>>>(ws);
  k3_intra<<<dim3(HW4_ / 128, B_), 128, 0, stream>>>(x, cm, ws);
  k4_final<<<1, 128, 0, stream>>>(ws, (float*)d_out);
}